// Round 2
// baseline (119.977 us; speedup 1.0000x reference)
//
#include <hip/hip_runtime.h>
#include <hip/hip_bf16.h>

#define BLK 256
#define SPLITS 22                 // scan splits (grid.x)
#define FRTOT 1584                // total B-fragments (22*72); slots = 50688
#define FPS (FRTOT / SPLITS)      // 72 frags per split (block)
#define WFRAGS (FPS / 4)          // 18 frags per wave (disjoint quarter)
#define NSLOT (FRTOT * 32)        // 50688 scan slots (>= N, padded w/ sentinel)
#define THRESH 0.1f
#define KEY_MAX 0xFFFFFFFFu
#define ONE_BF ((unsigned short)0x3F80)  // bf16(1.0)

typedef __attribute__((ext_vector_type(8))) short short8;
typedef __attribute__((ext_vector_type(16))) float floatx16;

// bf16 round-to-nearest-even helpers
__device__ __forceinline__ unsigned short f2bf(float x) {
    unsigned u = __float_as_uint(x);
    unsigned r = u + 0x7FFFu + ((u >> 16) & 1u);
    return (unsigned short)(r >> 16);
}
__device__ __forceinline__ float bf2f(unsigned short h) {
    return __uint_as_float(((unsigned)h) << 16);
}

// Order-preserving float->uint map: min in key space == min in float space.
__device__ __forceinline__ unsigned f2key(float f) {
    unsigned b = __float_as_uint(f);
    return (b & 0x80000000u) ? ~b : (b | 0x80000000u);
}
__device__ __forceinline__ float key2f(unsigned k) {
    return __uint_as_float((k & 0x80000000u) ? (k & 0x7FFFFFFFu) : ~k);
}

// min with DPP row_ror permute (2 VALU). CTRL: 0x120+N = row_ror:N (16-lane rows).
template <int CTRL>
__device__ __forceinline__ float dpp_ror_min(float v) {
    const int i = __float_as_int(v);
    const int p = __builtin_amdgcn_update_dpp(i, i, CTRL, 0xF, 0xF, false);
    return fminf(v, __int_as_float(p));
}

// Prep: pack scan points into global B-fragments (split-bf16, K=16), init
// gmin + out. B k-dims per scan point (s' = -2s): [sxh,sxl,sxh,sxl,
// syh,syl,syh,syl, szh,szl,szh,szl, 1,1, s2h,s2l]. Layout: lane L of the
// consuming wave reads fragbuf[f*64 + L] (lanes 0-31: k0-7, 32-63: k8-15).
__global__ __launch_bounds__(BLK) void pdl_prep(const float* __restrict__ scan,
                                                uint4* __restrict__ fragbuf,
                                                unsigned* __restrict__ gmin,
                                                float* __restrict__ out,
                                                int N, int Mpad) {
    const int n = blockIdx.x * BLK + threadIdx.x;
    if (n == 0) out[0] = 0.0f;
    if (n < Mpad) gmin[n] = KEY_MAX;
    if (n >= NSLOT) return;

    unsigned short k[16];
    if (n < N) {
        const float x = scan[3 * n + 0], y = scan[3 * n + 1], z = scan[3 * n + 2];
        const float s2 = fmaf(x, x, fmaf(y, y, z * z));
        const float cx = -2.0f * x, cy = -2.0f * y, cz = -2.0f * z;
        const unsigned short xh = f2bf(cx); const unsigned short xl = f2bf(cx - bf2f(xh));
        const unsigned short yh = f2bf(cy); const unsigned short yl = f2bf(cy - bf2f(yh));
        const unsigned short zh = f2bf(cz); const unsigned short zl = f2bf(cz - bf2f(zh));
        const unsigned short wh = f2bf(s2); const unsigned short wl = f2bf(s2 - bf2f(wh));
        k[0] = xh; k[1] = xl; k[2] = xh; k[3] = xl;
        k[4] = yh; k[5] = yl; k[6] = yh; k[7] = yl;
        k[8] = zh; k[9] = zl; k[10] = zh; k[11] = zl;
        k[12] = ONE_BF; k[13] = ONE_BF;
        k[14] = wh; k[15] = wl;
    } else {  // padded slot: d2 = t2 + 1e30 -> never the min
#pragma unroll
        for (int i = 0; i < 16; ++i) k[i] = 0;
        k[12] = ONE_BF; k[13] = ONE_BF;
        k[14] = f2bf(1e30f); k[15] = 0;
    }

    const int g = n >> 5, c = n & 31;
    uint4 lo, hi;
    lo.x = (unsigned)k[0] | ((unsigned)k[1] << 16);
    lo.y = (unsigned)k[2] | ((unsigned)k[3] << 16);
    lo.z = (unsigned)k[4] | ((unsigned)k[5] << 16);
    lo.w = (unsigned)k[6] | ((unsigned)k[7] << 16);
    hi.x = (unsigned)k[8] | ((unsigned)k[9] << 16);
    hi.y = (unsigned)k[10] | ((unsigned)k[11] << 16);
    hi.z = (unsigned)k[12] | ((unsigned)k[13] << 16);
    hi.w = (unsigned)k[14] | ((unsigned)k[15] << 16);
    fragbuf[(size_t)g * 64 + c] = lo;        // lanes 0-31: k = 0..7
    fragbuf[(size_t)g * 64 + 32 + c] = hi;   // lanes 32-63: k = 8..15
}

// A-frag k-dims: [txh,txh,txl,txl, tyh,tyh,tyl,tyl] (lanes 0-31),
//                [tzh,tzh,tzl,tzl, t2h,t2l, 1,1]    (lanes 32-63).
__device__ __forceinline__ short8 make_A(const float* __restrict__ tmpl, int m, bool hi) {
    const float x = tmpl[3 * m + 0], y = tmpl[3 * m + 1], z = tmpl[3 * m + 2];
    const float t2 = fmaf(x, x, fmaf(y, y, z * z));
    const unsigned short xh = f2bf(x); const unsigned short xl = f2bf(x - bf2f(xh));
    const unsigned short yh = f2bf(y); const unsigned short yl = f2bf(y - bf2f(yh));
    const unsigned short zh = f2bf(z); const unsigned short zl = f2bf(z - bf2f(zh));
    const unsigned short wh = f2bf(t2); const unsigned short wl = f2bf(t2 - bf2f(wh));
    short8 A;
    A[0] = (short)(hi ? zh : xh);
    A[1] = (short)(hi ? zh : xh);
    A[2] = (short)(hi ? zl : xl);
    A[3] = (short)(hi ? zl : xl);
    A[4] = (short)(hi ? wh : yh);
    A[5] = (short)(hi ? wl : yh);
    A[6] = (short)(hi ? ONE_BF : yl);
    A[7] = (short)(hi ? ONE_BF : yl);
    return A;
}

// Epilogue: min over 32 scan-cols per 32-lane half: 4x DPP row_ror min +
// ds_swizzle xor-16 + min. C/D: col=lane&31, row=(r&3)+8*(r>>2)+4*(lane>>5).
__device__ __forceinline__ void reduce_store(floatx16 mn, int mbase, int lane,
                                             unsigned* __restrict__ gmin) {
#pragma unroll
    for (int r = 0; r < 16; ++r) {
        float v = mn[r];
        v = dpp_ror_min<0x128>(v);  // row_ror:8
        v = dpp_ror_min<0x124>(v);  // row_ror:4
        v = dpp_ror_min<0x122>(v);  // row_ror:2
        v = dpp_ror_min<0x121>(v);  // row_ror:1
        const int sw = __builtin_amdgcn_ds_swizzle(__float_as_int(v), 0x401F);
        v = fminf(v, __int_as_float(sw));  // xor lane^16 within 32-group
        if ((lane & 31) == 0) {
            const int row = (r & 3) + 8 * (r >> 2) + ((lane >> 5) << 2);
            atomicMin(&gmin[mbase + row], f2key(v));
        }
    }
}

// Main: NO LDS, NO barrier. Frag-split TA=4: each block owns 128 template
// rows; all 4 waves build the SAME four A-frags but stream a DISJOINT
// quarter (18 frags) of the split's B-fragments, merging via gmin atomics.
// vs R1 (TA=2, all waves same frags): 4x less global traffic (342->85.5 MB),
// no same-address pile-ups, 8 MFMA + 64 min3 per 2KB pair (~200 cyc issue)
// fully covers ~200cyc L2 latency at 3 waves/SIMD. Live set ~155 VGPR ->
// launch_bounds(256,3) (cap 170) avoids the R1 spill at cap 128.
__global__ __launch_bounds__(BLK, 3) void pdl_main(const float* __restrict__ tmpl,
                                                   const uint4* __restrict__ fragbuf,
                                                   unsigned* __restrict__ gmin,
                                                   int M) {
    const int tid = threadIdx.x;
    const int wave = tid >> 6, lane = tid & 63;
    const bool hi = (lane >= 32);

    // Block owns rows [mbase, mbase+128); four A-frags of 32 rows each.
    const int mbase = blockIdx.y * 128;
    int m0 = mbase + (lane & 31);        if (m0 > M - 1) m0 = M - 1;  // clamped
    int m1 = mbase + 32 + (lane & 31);   if (m1 > M - 1) m1 = M - 1;  // dup rows;
    int m2 = mbase + 64 + (lane & 31);   if (m2 > M - 1) m2 = M - 1;  // masked via
    int m3 = mbase + 96 + (lane & 31);   if (m3 > M - 1) m3 = M - 1;  // final m<M
    const short8 A0 = make_A(tmpl, m0, hi);
    const short8 A1 = make_A(tmpl, m1, hi);
    const short8 A2 = make_A(tmpl, m2, hi);
    const short8 A3 = make_A(tmpl, m3, hi);

    floatx16 mn0, mn1, mn2, mn3, zacc;
#pragma unroll
    for (int r = 0; r < 16; ++r) {
        mn0[r] = 3e30f; mn1[r] = 3e30f; mn2[r] = 3e30f; mn3[r] = 3e30f;
        zacc[r] = 0.0f;
    }

    // This wave's disjoint fragment range; lane-indexed base pointer.
    const uint4* fb = fragbuf +
        (size_t)(blockIdx.x * FPS + wave * WFRAGS) * 64 + lane;

    union U { uint4 u; short8 s; };
    // Register double-buffer: prefetch next pair while computing current.
    // Over-reads 2 frags past the end (fragbuf allocated FRTOT+2; harmless).
    uint4 p0 = fb[0];
    uint4 p1 = fb[64];
#pragma unroll 1
    for (int f = 0; f < WFRAGS; f += 2) {
        U c0, c1; c0.u = p0; c1.u = p1;
        p0 = fb[(size_t)(f + 2) * 64];
        p1 = fb[(size_t)(f + 3) * 64];
        // One d-pair (32 VGPR) live at a time; min3 per element.
#define PDL_STEP(Af, mnf)                                                          \
        {                                                                          \
            const floatx16 d0 =                                                    \
                __builtin_amdgcn_mfma_f32_32x32x16_bf16(Af, c0.s, zacc, 0, 0, 0);  \
            const floatx16 d1 =                                                    \
                __builtin_amdgcn_mfma_f32_32x32x16_bf16(Af, c1.s, zacc, 0, 0, 0);  \
            _Pragma("unroll")                                                      \
            for (int r = 0; r < 16; ++r)                                           \
                mnf[r] = fminf(fminf(d0[r], d1[r]), mnf[r]);                       \
        }
        PDL_STEP(A0, mn0)
        PDL_STEP(A1, mn1)
        PDL_STEP(A2, mn2)
        PDL_STEP(A3, mn3)
#undef PDL_STEP
    }

    reduce_store(mn0, mbase, lane, gmin);
    reduce_store(mn1, mbase + 32, lane, gmin);
    reduce_store(mn2, mbase + 64, lane, gmin);
    reduce_store(mn3, mbase + 96, lane, gmin);
}

// Unmap, threshold, block-reduce, atomicAdd.
__global__ __launch_bounds__(BLK) void pdl_final(const unsigned* __restrict__ gmin,
                                                 float* __restrict__ out, int M) {
    const int m = blockIdx.x * BLK + threadIdx.x;
    float s = 0.0f;
    if (m < M) {
        const float v = key2f(gmin[m]);
        if (v < THRESH) s = v;
    }
#pragma unroll
    for (int off = 32; off > 0; off >>= 1) s += __shfl_down(s, off, 64);

    __shared__ float ls[BLK / 64];
    const int lane = threadIdx.x & 63;
    const int w = threadIdx.x >> 6;
    if (lane == 0) ls[w] = s;
    __syncthreads();
    if (threadIdx.x == 0) {
        float t = 0.0f;
#pragma unroll
        for (int i = 0; i < BLK / 64; ++i) t += ls[i];
        atomicAdd(out, t);
    }
}

extern "C" void kernel_launch(void* const* d_in, const int* in_sizes, int n_in,
                              void* d_out, int out_size, void* d_ws, size_t ws_size,
                              hipStream_t stream) {
    const float* scan = (const float*)d_in[0];   // [N,3] fp32
    const float* tmpl = (const float*)d_in[1];   // [M,3] fp32
    float* out = (float*)d_out;                  // scalar fp32

    const int N = in_sizes[0] / 3;               // 50000
    const int M = in_sizes[1] / 3;               // 6890

    const int tGroups = (M + 127) / 128;         // 54 blocks of 128 templates
    const int Mpad = ((M + 31) / 32) * 32 + 128; // gmin covers clamped-dup rows

    // ws: gmin [0, 64KB) ; fragbuf at 64KB: (FRTOT+2) frags x 1KB ~ 1.6 MB
    unsigned* gmin = (unsigned*)d_ws;
    uint4* fragbuf = (uint4*)((char*)d_ws + 65536);

    pdl_prep<<<(NSLOT + BLK - 1) / BLK, BLK, 0, stream>>>(scan, fragbuf, gmin,
                                                          out, N, Mpad);

    dim3 grid(SPLITS, tGroups);
    pdl_main<<<grid, BLK, 0, stream>>>(tmpl, fragbuf, gmin, M);

    pdl_final<<<(M + BLK - 1) / BLK, BLK, 0, stream>>>(gmin, out, M);
}

// Round 3
// 73.033 us; speedup vs baseline: 1.6428x; 1.6428x over previous
//
#include <hip/hip_runtime.h>
#include <hip/hip_bf16.h>

#define BLK 256
#define WPB 4                      // waves per block
#define TB 12                      // template B-frags resident per wave
#define TSPLITS 18                 // 216 template frags / TB
#define SA 11                      // scan A-frags streamed per wave
#define SSPLITS 144                // 1584 scan frags / SA
#define FRTOT 1584                 // total scan fragments; slots = 50688
#define NSLOT (FRTOT * 32)         // 50688 scan slots (>= N, padded w/ sentinel)
#define MFR 216                    // template fragments
#define MPAD (MFR * 32)            // 6912 padded template columns
#define THRESH 0.1f
#define KEY_MAX 0xFFFFFFFFu
#define ONE_BF ((unsigned short)0x3F80)  // bf16(1.0)

typedef __attribute__((ext_vector_type(8))) short short8;
typedef __attribute__((ext_vector_type(16))) float floatx16;

// bf16 round-to-nearest-even helpers
__device__ __forceinline__ unsigned short f2bf(float x) {
    unsigned u = __float_as_uint(x);
    unsigned r = u + 0x7FFFu + ((u >> 16) & 1u);
    return (unsigned short)(r >> 16);
}
__device__ __forceinline__ float bf2f(unsigned short h) {
    return __uint_as_float(((unsigned)h) << 16);
}

// Order-preserving float->uint map: min in key space == min in float space.
__device__ __forceinline__ unsigned f2key(float f) {
    unsigned b = __float_as_uint(f);
    return (b & 0x80000000u) ? ~b : (b | 0x80000000u);
}
__device__ __forceinline__ float key2f(unsigned k) {
    return __uint_as_float((k & 0x80000000u) ? (k & 0x7FFFFFFFu) : ~k);
}

// Prep: build BOTH fragment buffers.
//   Scan A-frags (rows; pattern identical to previous rounds' scan pattern,
//   -2 folded into coords): k0-3 [sxh,sxl,sxh,sxl] k4-7 [syh,syl,syh,syl]
//   k8-11 [szh,szl,szh,szl] k12,13 [1,1] k14,15 [s2h,s2l].
//   Template B-frags (cols; pattern identical to previous rounds' make_A):
//   k0-3 [txh,txh,txl,txl] k4-7 [tyh,tyh,tyl,tyl] k8-11 [tzh,tzh,tzl,tzl]
//   k12,13 [t2h,t2l] k14,15 [1,1].
// Same k-slot pairing as before -> bit-identical MFMA dot products.
// Layout (both buffers): frag g, point c=(n&31): slot g*64+c = k0-7 packed,
// slot g*64+32+c = k8-15; consuming lane L reads frag[g*64+L].
__global__ __launch_bounds__(BLK) void pdl_prep(const float* __restrict__ scan,
                                                const float* __restrict__ tmpl,
                                                uint4* __restrict__ afrag,
                                                uint4* __restrict__ bfrag,
                                                unsigned* __restrict__ gmin,
                                                float* __restrict__ out,
                                                int N, int M) {
    const int n = blockIdx.x * BLK + threadIdx.x;
    if (n == 0) out[0] = 0.0f;

    if (n < MPAD) {
        gmin[n] = KEY_MAX;
        // template B-frag slot
        unsigned short q[16];
        if (n < M) {
            const float x = tmpl[3 * n + 0], y = tmpl[3 * n + 1], z = tmpl[3 * n + 2];
            const float t2 = fmaf(x, x, fmaf(y, y, z * z));
            const unsigned short xh = f2bf(x); const unsigned short xl = f2bf(x - bf2f(xh));
            const unsigned short yh = f2bf(y); const unsigned short yl = f2bf(y - bf2f(yh));
            const unsigned short zh = f2bf(z); const unsigned short zl = f2bf(z - bf2f(zh));
            const unsigned short wh = f2bf(t2); const unsigned short wl = f2bf(t2 - bf2f(wh));
            q[0] = xh; q[1] = xh; q[2] = xl; q[3] = xl;
            q[4] = yh; q[5] = yh; q[6] = yl; q[7] = yl;
            q[8] = zh; q[9] = zh; q[10] = zl; q[11] = zl;
            q[12] = wh; q[13] = wl;
            q[14] = ONE_BF; q[15] = ONE_BF;
        } else {  // padded template col: d2 = s2 >= 0; gmin[col>=M] ignored by final
#pragma unroll
            for (int i = 0; i < 16; ++i) q[i] = 0;
            q[14] = ONE_BF; q[15] = ONE_BF;
        }
        const int g = n >> 5, c = n & 31;
        uint4 lo, hi;
        lo.x = (unsigned)q[0] | ((unsigned)q[1] << 16);
        lo.y = (unsigned)q[2] | ((unsigned)q[3] << 16);
        lo.z = (unsigned)q[4] | ((unsigned)q[5] << 16);
        lo.w = (unsigned)q[6] | ((unsigned)q[7] << 16);
        hi.x = (unsigned)q[8] | ((unsigned)q[9] << 16);
        hi.y = (unsigned)q[10] | ((unsigned)q[11] << 16);
        hi.z = (unsigned)q[12] | ((unsigned)q[13] << 16);
        hi.w = (unsigned)q[14] | ((unsigned)q[15] << 16);
        bfrag[(size_t)g * 64 + c] = lo;
        bfrag[(size_t)g * 64 + 32 + c] = hi;
    }

    if (n >= NSLOT) return;

    unsigned short k[16];
    if (n < N) {
        const float x = scan[3 * n + 0], y = scan[3 * n + 1], z = scan[3 * n + 2];
        const float s2 = fmaf(x, x, fmaf(y, y, z * z));
        const float cx = -2.0f * x, cy = -2.0f * y, cz = -2.0f * z;
        const unsigned short xh = f2bf(cx); const unsigned short xl = f2bf(cx - bf2f(xh));
        const unsigned short yh = f2bf(cy); const unsigned short yl = f2bf(cy - bf2f(yh));
        const unsigned short zh = f2bf(cz); const unsigned short zl = f2bf(cz - bf2f(zh));
        const unsigned short wh = f2bf(s2); const unsigned short wl = f2bf(s2 - bf2f(wh));
        k[0] = xh; k[1] = xl; k[2] = xh; k[3] = xl;
        k[4] = yh; k[5] = yl; k[6] = yh; k[7] = yl;
        k[8] = zh; k[9] = zl; k[10] = zh; k[11] = zl;
        k[12] = ONE_BF; k[13] = ONE_BF;
        k[14] = wh; k[15] = wl;
    } else {  // padded scan row: d2 = t2 + 1e30 -> never the min
#pragma unroll
        for (int i = 0; i < 16; ++i) k[i] = 0;
        k[12] = ONE_BF; k[13] = ONE_BF;
        k[14] = f2bf(1e30f); k[15] = 0;
    }

    const int g = n >> 5, c = n & 31;
    uint4 lo, hi;
    lo.x = (unsigned)k[0] | ((unsigned)k[1] << 16);
    lo.y = (unsigned)k[2] | ((unsigned)k[3] << 16);
    lo.z = (unsigned)k[4] | ((unsigned)k[5] << 16);
    lo.w = (unsigned)k[6] | ((unsigned)k[7] << 16);
    hi.x = (unsigned)k[8] | ((unsigned)k[9] << 16);
    hi.y = (unsigned)k[10] | ((unsigned)k[11] << 16);
    hi.z = (unsigned)k[12] | ((unsigned)k[13] << 16);
    hi.w = (unsigned)k[14] | ((unsigned)k[15] << 16);
    afrag[(size_t)g * 64 + c] = lo;        // lanes 0-31: k = 0..7
    afrag[(size_t)g * 64 + 32 + c] = hi;   // lanes 32-63: k = 8..15
}

// Main, role-swapped: A = scan rows (streamed), B = template cols (resident).
// D[r][lane]: row=scan=(r&3)+8*(r>>2)+4*(lane>>5), col=template=lane&31.
// The min over scans collapses the 16 d-regs IMMEDIATELY (min3 tree) into ONE
// running-min VGPR per resident template frag -> accumulator state = TB regs
// instead of 16*TA (the R1/R2 AGPR/spill catastrophe: VGPR_Count=72 +9.5MB
// scratch writes). Live set ~130 VGPR -> real 3 waves/SIMD, no spills.
// 4 waves/block share one template split; block-level LDS merge cuts global
// atomic volume 4x (995K -> 249K lanes).
__global__ __launch_bounds__(BLK, 3) void pdl_main(const uint4* __restrict__ afrag,
                                                   const uint4* __restrict__ bfrag,
                                                   unsigned* __restrict__ gmin) {
    const int tid = threadIdx.x;
    const int wave = tid >> 6, lane = tid & 63;
    const int tsplit = blockIdx.x;                 // 0..17: which 384 template cols
    const int ssplit = blockIdx.y * WPB + wave;    // 0..143: which 11 scan frags

    __shared__ unsigned lmin[TB * 32];
#pragma unroll 2
    for (int i = tid; i < TB * 32; i += BLK) lmin[i] = KEY_MAX;

    union U { uint4 u; short8 s; };

    // Resident template B-frags (same for all 4 waves of the block).
    const uint4* bb = bfrag + (size_t)(tsplit * TB) * 64 + lane;
    U B[TB];
#pragma unroll
    for (int j = 0; j < TB; ++j) B[j].u = bb[(size_t)j * 64];

    float mn[TB];
#pragma unroll
    for (int j = 0; j < TB; ++j) mn[j] = 3e30f;

    floatx16 zacc;
#pragma unroll
    for (int r = 0; r < 16; ++r) zacc[r] = 0.0f;

    __syncthreads();  // lmin ready (placed after load-issue to overlap)

    // Stream this wave's 11 scan A-frags, register double-buffered.
    // Over-reads 1 frag past the end (afrag allocated FRTOT+2; harmless).
    const uint4* ab = afrag + (size_t)(ssplit * SA) * 64 + lane;
    uint4 p = ab[0];
#pragma unroll 1
    for (int f = 0; f < SA; ++f) {
        U a; a.u = p;
        p = ab[(size_t)(f + 1) * 64];
#pragma unroll
        for (int j = 0; j < TB; ++j) {
            const floatx16 d =
                __builtin_amdgcn_mfma_f32_32x32x16_bf16(a.s, B[j].s, zacc, 0, 0, 0);
            // min over the 16 scan rows this lane holds (min3-friendly triples)
            const float t0 = fminf(fminf(d[0], d[1]), d[2]);
            const float t1 = fminf(fminf(d[3], d[4]), d[5]);
            const float t2 = fminf(fminf(d[6], d[7]), d[8]);
            const float t3 = fminf(fminf(d[9], d[10]), d[11]);
            const float t4 = fminf(fminf(d[12], d[13]), d[14]);
            const float u0 = fminf(fminf(t0, t1), t2);
            const float u1 = fminf(fminf(t3, t4), d[15]);
            mn[j] = fminf(fminf(u0, u1), mn[j]);
        }
    }

    // Merge complementary row-halves (lane ^ 32 holds the other 16 scan rows
    // of the same template column), then block-level LDS merge.
#pragma unroll
    for (int j = 0; j < TB; ++j) {
        const float o = __shfl_xor(mn[j], 32, 64);
        const float v = fminf(mn[j], o);
        if (lane < 32) atomicMin(&lmin[j * 32 + lane], f2key(v));
    }
    __syncthreads();

    const int mbase = tsplit * (TB * 32);
#pragma unroll 2
    for (int i = tid; i < TB * 32; i += BLK) atomicMin(&gmin[mbase + i], lmin[i]);
}

// Unmap, threshold, block-reduce, atomicAdd.
__global__ __launch_bounds__(BLK) void pdl_final(const unsigned* __restrict__ gmin,
                                                 float* __restrict__ out, int M) {
    const int m = blockIdx.x * BLK + threadIdx.x;
    float s = 0.0f;
    if (m < M) {
        const float v = key2f(gmin[m]);
        if (v < THRESH) s = v;
    }
#pragma unroll
    for (int off = 32; off > 0; off >>= 1) s += __shfl_down(s, off, 64);

    __shared__ float ls[BLK / 64];
    const int lane = threadIdx.x & 63;
    const int w = threadIdx.x >> 6;
    if (lane == 0) ls[w] = s;
    __syncthreads();
    if (threadIdx.x == 0) {
        float t = 0.0f;
#pragma unroll
        for (int i = 0; i < BLK / 64; ++i) t += ls[i];
        atomicAdd(out, t);
    }
}

extern "C" void kernel_launch(void* const* d_in, const int* in_sizes, int n_in,
                              void* d_out, int out_size, void* d_ws, size_t ws_size,
                              hipStream_t stream) {
    const float* scan = (const float*)d_in[0];   // [N,3] fp32
    const float* tmpl = (const float*)d_in[1];   // [M,3] fp32
    float* out = (float*)d_out;                  // scalar fp32

    const int N = in_sizes[0] / 3;               // 50000
    const int M = in_sizes[1] / 3;               // 6890

    // ws: gmin [0, 64KB) ; afrag: (FRTOT+2) x 1KB ; bfrag: MFR x 1KB
    unsigned* gmin = (unsigned*)d_ws;
    uint4* afrag = (uint4*)((char*)d_ws + 65536);
    uint4* bfrag = (uint4*)((char*)d_ws + 65536 + (size_t)(FRTOT + 2) * 1024);

    pdl_prep<<<(NSLOT + BLK - 1) / BLK, BLK, 0, stream>>>(scan, tmpl, afrag, bfrag,
                                                          gmin, out, N, M);

    dim3 grid(TSPLITS, SSPLITS / WPB);           // (18, 36)
    pdl_main<<<grid, BLK, 0, stream>>>(afrag, bfrag, gmin);

    pdl_final<<<(M + BLK - 1) / BLK, BLK, 0, stream>>>(gmin, out, M);
}